// Round 17
// baseline (155.106 us; speedup 1.0000x reference)
//
#include <hip/hip_runtime.h>

// CTC forward loss, MI355X — fwd/bwd split (bwd = verified fwd machinery in
// reversed state coords rho=200-s, reversed labels). R17:
//  * SMT packing: block = 512 threads = 8 waves = 4 batch elements (fwd+bwd
//    each). 2 waves per SIMD -> stalls (exchange RAW, load latency) of one
//    wave hide under the other's VALU issue. R16 had 1 wave/SIMD: all stalls
//    exposed (876 cyc/iter vs ~430 issue).
//  * records BF16-PACKED (56 f32/rec), triple-buffered global->reg prefetch,
//    LDS only for the 6-op/iter neighbor exchange. Numerics identical to R16.

#define TT 2000
#define BB 64
#define VV 128
#define LL 100
#define RECW 56
#define REC_BASE 256
#define NEGF (-1e30f)
#define L2E 1.44269504f
#define LN2 0.69314718f

#define SB_STATE (REC_BASE + BB * TT * RECW)
#define AREA 336

__device__ __forceinline__ float wave_max64(float v) {
#pragma unroll
  for (int o = 32; o > 0; o >>= 1) v = fmaxf(v, __shfl_xor(v, o, 64));
  return v;
}
__device__ __forceinline__ float wave_sum64(float v) {
#pragma unroll
  for (int o = 32; o > 0; o >>= 1) v += __shfl_xor(v, o, 64);
  return v;
}
__device__ __forceinline__ float blo(unsigned u) { return __uint_as_float(u << 16); }
__device__ __forceinline__ float bhi(unsigned u) { return __uint_as_float(u & 0xFFFF0000u); }
__device__ __forceinline__ unsigned b16(float x) {
  unsigned b = __float_as_uint(x);
  return (b + 0x7FFFu + ((b >> 16) & 1u)) >> 16;   // RNE
}

__global__ __launch_bounds__(256) void k_gather(const float* __restrict__ acts,
                                                const int* __restrict__ target,
                                                float* __restrict__ ws) {
  const int lane = threadIdx.x & 63;
  const int w = threadIdx.x >> 6;
  const int r = blockIdx.x * 4 + w;          // r = t*BB + b
  if (r >= TT * BB) return;
  const int b = r % BB;
  const int t = r / BB;
  const float* row = acts + (size_t)r * VV;
  float x0 = row[lane];
  float x1 = row[lane + 64];
  float m = wave_max64(fmaxf(x0, x1));
  float e = __builtin_exp2f((x0 - m) * L2E) + __builtin_exp2f((x1 - m) * L2E);
  float s = wave_sum64(e);
  float lse = m + __builtin_log2f(s) * LN2;
  const int* lab = target + b * LL;
  const int j = lane;
  int ilo = (2 * j < 100) ? 2 * j : 99;
  int ihi = (2 * j + 1 < 100) ? 2 * j + 1 : 99;
  int cl = lab[ilo], ch = lab[ihi];
  float ya = __shfl(x0, cl & 63, 64), yb = __shfl(x1, cl & 63, 64);
  float ylo = (cl < 64) ? ya : yb;
  float yc = __shfl(x0, ch & 63, 64), yd = __shfl(x1, ch & 63, 64);
  float yhi = (ch < 64) ? yc : yd;
  float glo = (j < 50) ? (ylo - lse) : NEGF;
  float ghi = (j < 50) ? (yhi - lse) : NEGF;
  float gb = __shfl(x0, 0, 64) - lse;
  float gm = wave_max64(fmaxf(fmaxf(glo, ghi), gb));
  float qlo = __builtin_exp2f((glo - gm) * L2E);
  float qhi = __builtin_exp2f((ghi - gm) * L2E);
  unsigned u = b16(qlo) | (b16(qhi) << 16);
  unsigned* rec = (unsigned*)(ws + REC_BASE + ((size_t)b * TT + t) * RECW);
  if (j < 50) rec[2 + j] = u;
  if (j == 50) rec[52] = 0u;
  if (j == 0) {
    ((float*)rec)[0] = __builtin_exp2f((gb - gm) * L2E);
    ((float*)rec)[1] = gm;
  }
}

#define BPER __builtin_amdgcn_ds_bpermute
#define CL50(x) ((x) < 0 ? 0 : ((x) > 50 ? 50 : (x)))

// per-buffer: 4x h(float2) + 8x packed q + 1x packed aY = 17 regs
#define DECLR(P) float2 P##h0, P##h1, P##h2, P##h3; \
                 unsigned P##b0, P##b1, P##b2, P##b3, P##c0, P##c1, P##c2, P##c3, P##uA

// global->reg prefetch of one 4-step block (13 plain loads)
#define PREF(P, bidx) do {                                                   \
  int bi_ = (bidx); bi_ = (bi_ < bcap) ? bi_ : bcap; if (bi_ < 0) bi_ = 0;   \
  const float* r0_ = recs_b + (size_t)(tA + TS * 4 * bi_) * RECW;            \
  P##h0 = *(const float2*)(r0_);                                             \
  P##h1 = *(const float2*)(r0_ + TS * RECW);                                 \
  P##h2 = *(const float2*)(r0_ + TS * 2 * RECW);                             \
  P##h3 = *(const float2*)(r0_ + TS * 3 * RECW);                             \
  P##b0 = ((const unsigned*)r0_)[pbofs];                                     \
  P##c0 = ((const unsigned*)r0_)[pcofs];                                     \
  P##b1 = ((const unsigned*)(r0_ + TS * RECW))[pbofs];                       \
  P##c1 = ((const unsigned*)(r0_ + TS * RECW))[pcofs];                       \
  P##b2 = ((const unsigned*)(r0_ + TS * 2 * RECW))[pbofs];                   \
  P##c2 = ((const unsigned*)(r0_ + TS * 2 * RECW))[pcofs];                   \
  P##b3 = ((const unsigned*)(r0_ + TS * 3 * RECW))[pbofs];                   \
  P##c3 = ((const unsigned*)(r0_ + TS * 3 * RECW))[pcofs];                   \
  P##uA = ((const unsigned*)r0_)[payofs];                                    \
} while (0)

// top-down in-place update; NH = halo pairs updated (3/2/1/0)
#define STEP(qbv, gmv, cx, cy, bx, by, ay, NH) do {                          \
  const float qb_ = (qbv); msum += (gmv);                                    \
  o3 = __builtin_fmaf(cs_o3, o1, o3 + o2) * (cy);                            \
  o2 = (o2 + o1) * qb_;                                                      \
  o1 = __builtin_fmaf(cs_o1, h1, o1 + o0) * (cx);                            \
  o0 = (o0 + h1) * qb_;                                                      \
  if (NH >= 1) { h1 = __builtin_fmaf(cs_h1, h3, h1 + h2) * (by);             \
                 h2 = (h2 + h3) * qb_; }                                     \
  if (NH >= 2) { h3 = __builtin_fmaf(cs_h3, h5, h3 + h4) * (bx);             \
                 h4 = (h4 + h5) * qb_; }                                     \
  if (NH >= 3) { h5 = __builtin_fmaf(cs_h5, h7, h5 + h6) * (ay);             \
                 h6 = (h6 + h7) * qb_; }                                     \
} while (0)

// unpack to canonical (bx,by,cx,cy)
#define UQ(P, K, QV) float4 QV; do {                                         \
  if constexpr (DIR) {                                                       \
    QV = (float4){bhi(P##b##K), blo(P##b##K),                                \
                  bhi(P##c##K) * cmask, blo(P##c##K) * cmask};               \
  } else {                                                                   \
    QV = (float4){blo(P##b##K), bhi(P##b##K), blo(P##c##K), bhi(P##c##K)};   \
  }                                                                          \
} while (0)

// 4 steps + exchange WRITE
#define COMPA(P) do {                                                        \
  UQ(P, 0, q0_); UQ(P, 1, q1_); UQ(P, 2, q2_); UQ(P, 3, q3_);                \
  float aYv = DIR ? blo(P##uA) : bhi(P##uA);                                 \
  STEP(P##h0.x, P##h0.y, q0_.z, q0_.w, q0_.x, q0_.y, aYv, 3);                \
  STEP(P##h1.x, P##h1.y, q1_.z, q1_.w, q1_.x, q1_.y, 0.f, 2);                \
  STEP(P##h2.x, P##h2.y, q2_.z, q2_.w, q2_.x, q2_.y, 0.f, 1);                \
  STEP(P##h3.x, P##h3.y, q3_.z, q3_.w, 0.f, 0.f, 0.f, 0);                    \
  *(float4*)(exb + 4 * l) = (float4){o0, o1, o2, o3};                        \
  ((int*)exb)[256 + l] = offs;                                               \
} while (0)

// exchange READ + reconcile (numerics identical to R13/R15/R16)
#define FINL() do {                                                          \
  asm volatile("" ::: "memory");                                             \
  float4 L1_ = *(const float4*)(exb + 4 * ((l >= 1) ? (l - 1) : 0));         \
  float4 L2_ = *(const float4*)(exb + 4 * ((l >= 2) ? (l - 2) : 0));         \
  int ro1_ = ((const int*)exb)[256 + ((l >= 1) ? (l - 1) : 0)];              \
  int ro2_ = ((const int*)exb)[256 + ((l >= 2) ? (l - 2) : 0)];              \
  ro1_ = (l >= 1) ? ro1_ : -(1 << 29);                                       \
  ro2_ = (l >= 2) ? ro2_ : -(1 << 29);                                       \
  float m_ = fmaxf(fmaxf(o0, o1), fmaxf(o2, o3));                            \
  int eb_ = (int)((__float_as_uint(m_) >> 23) & 255u);                       \
  int t1_ = offs + (eb_ ? (eb_ - 127) : -126);                               \
  int mx_ = (ro1_ > ro2_) ? ro1_ : ro2_;                                     \
  int onew_ = (t1_ > mx_) ? t1_ : mx_;                                       \
  int ds_ = offs - onew_;  ds_ = (ds_ < -300) ? -300 : ds_;                  \
  int d1_ = ro1_ - onew_, d2_ = ro2_ - onew_;                                \
  d1_ = (d1_ < -300) ? -300 : d1_;                                           \
  d2_ = (d2_ < -300) ? -300 : d2_;                                           \
  o0 = ldexpf(o0, ds_); o1 = ldexpf(o1, ds_);                                \
  o2 = ldexpf(o2, ds_); o3 = ldexpf(o3, ds_);                                \
  h1 = ldexpf(L1_.w, d1_) * msk1;                                            \
  h2 = ldexpf(L1_.z, d1_) * msk2;                                            \
  h3 = ldexpf(L1_.y, d1_) * msk3;                                            \
  h4 = ldexpf(L1_.x, d1_) * msk4;                                            \
  h5 = ldexpf(L2_.w, d2_) * msk5;                                            \
  h6 = ldexpf(L2_.z, d2_) * msk6;                                            \
  h7 = ldexpf(L2_.y, d2_) * msk7;                                            \
  offs = onew_;                                                              \
} while (0)

template <int DIR>
__device__ __forceinline__ void run_chain(const int* __restrict__ target,
                                          const int* __restrict__ lablens,
                                          const float* __restrict__ recs_b,
                                          float* exb, int size, int b, int l,
                                          float* __restrict__ ws) {
  const int mid = (size - 1) >> 1;
  const int sizeP = DIR ? (size - 1 - mid) : (mid + 1);
  const int* lab = target + b * LL;
  const int lc = (l < 50) ? l : 50;
  const int tA = DIR ? (size - 2) : 1;
  constexpr int TS = DIR ? -1 : 1;
  const int bcap = DIR ? ((size - 5) >> 2) : 498;
  // packed-pair offsets (u32 index within record; +2 header)
  const int pbofs = 2 + (DIR ? CL50(50 - l) : CL50(l - 1));
  const int pcofs = 2 + (DIR ? CL50(49 - l) : CL50(l));
  const int payofs = 2 + (DIR ? CL50(51 - l) : CL50(l - 2));
  const float cmask = (l < 50) ? 1.f : 0.f;
  const int idx1 = ((l + 63) & 63) << 2;
  const float msk1 = (4 * l - 1 >= 0) ? 1.f : 0.f;
  const float msk2 = (4 * l - 2 >= 0) ? 1.f : 0.f;
  const float msk3 = (4 * l - 3 >= 0) ? 1.f : 0.f;
  const float msk4 = (4 * l - 4 >= 0) ? 1.f : 0.f;
  const float msk5 = (4 * l - 5 >= 0) ? 1.f : 0.f;
  const float msk6 = (4 * l - 6 >= 0) ? 1.f : 0.f;
  const float msk7 = (4 * l - 7 >= 0) ? 1.f : 0.f;
  // skip masks: fwd from lab ascending; bwd from reversed labels lab'[j]=lab[99-j]
  int i0, i1, i2, i3, i4, i5;
  if constexpr (DIR == 0) { i0 = 2*l+1; i1 = 2*l; i2 = 2*l-1; i3 = 2*l-2; i4 = 2*l-3; i5 = 2*l-4; }
  else { i0 = 98-2*l; i1 = 99-2*l; i2 = 100-2*l; i3 = 101-2*l; i4 = 102-2*l; i5 = 103-2*l; }
#define CLM(x) ((x) < 0 ? 0 : ((x) > 99 ? 99 : (x)))
  const int La = lab[CLM(i0)], Lb_ = lab[CLM(i1)], Lc = lab[CLM(i2)];
  const int Ld = lab[CLM(i3)], Le = lab[CLM(i4)], Lf = lab[CLM(i5)];
  const float cs_o3 = (La != Lb_) ? 1.f : 0.f;
  const float cs_o1 = (Lb_ != Lc) ? 1.f : 0.f;
  const float cs_h1 = (Lc != Ld) ? 1.f : 0.f;
  const float cs_h3 = (Ld != Le) ? 1.f : 0.f;
  const float cs_h5 = (Le != Lf) ? 1.f : 0.f;
  // init
  float o0 = 0.f, o1 = 0.f, o2 = 0.f, o3 = 0.f;
  float h1 = 0.f, h2 = 0.f, h3 = 0.f, h4 = 0.f, h5 = 0.f, h6 = 0.f, h7 = 0.f;
  int offs = 0;
  float msum;
  if constexpr (DIR == 0) {
    msum = recs_b[1];
    float q0i = blo(((const unsigned*)recs_b)[2]);   // q_lab[0]
    if (l == 0) { o0 = recs_b[0]; o1 = q0i; }
    if (l == 1) { h3 = q0i; h4 = recs_b[0]; }
    if (l == 2) { h7 = q0i; }
  } else {
    const float* recL = recs_b + (size_t)(size - 1) * RECW;
    msum = recL[1];
    const int Lbv = lablens[b];
    const int r0v = 200 - 2 * Lbv;   // rho of end state 2L; r0v+1 = rho of 2L-1
    auto gi = [&](int rho) -> float {
      if (rho != r0v && rho != r0v + 1) return 0.f;
      if ((rho & 1) == 0) return recL[0];
      int mm = 99 - ((rho - 1) >> 1);
      unsigned u = ((const unsigned*)recL)[2 + (mm >> 1)];
      return (mm & 1) ? bhi(u) : blo(u);
    };
    o0 = gi(4*l); o1 = gi(4*l+1); o2 = gi(4*l+2); o3 = gi(4*l+3);
    h1 = gi(4*l-1); h2 = gi(4*l-2); h3 = gi(4*l-3); h4 = gi(4*l-4);
    h5 = gi(4*l-5); h6 = gi(4*l-6); h7 = gi(4*l-7);
  }

  const int nb = (sizeP - 1) >> 2;
  DECLR(A); DECLR(B); DECLR(C);
  PREF(A, 0); PREF(B, 1);
  int blk = 0;
  for (; blk + 3 <= nb; blk += 3) {
    COMPA(A); PREF(C, blk + 2); FINL();
    COMPA(B); PREF(A, blk + 3); FINL();
    COMPA(C); PREF(B, blk + 4); FINL();
  }
  if (nb - blk >= 1) { COMPA(A); FINL(); }
  if (nb - blk >= 2) { COMPA(B); FINL(); }
  // tail (<=3 steps) + forward-only extra A-step
  {
    int rno1 = BPER(idx1, offs);
    int dtl = rno1 - offs;
    dtl = (dtl > 120) ? 120 : ((dtl < -300) ? -300 : dtl);
    for (int tau = 1 + 4 * nb; tau < sizeP; ++tau) {
      const float* rt = recs_b + (size_t)(DIR ? (size - 1 - tau) : tau) * RECW;
      float2 hh = *(const float2*)rt;
      float cx, cy;
      if constexpr (DIR == 0) {
        unsigned u = ((const unsigned*)rt)[2 + lc];   // pair lc (lc=50 -> zero pad)
        cx = blo(u); cy = bhi(u);
      } else {
        unsigned u = ((const unsigned*)rt)[2 + CL50(50 - l)];
        cx = bhi(u) * cmask; cy = blo(u) * cmask;
      }
      int rp = BPER(idx1, __float_as_int(o3));
      float p = ldexpf(__int_as_float(rp), dtl) * msk1;
      msum += hh.y;
      o3 = __builtin_fmaf(cs_o3, o1, o3 + o2) * cy;
      o2 = (o2 + o1) * hh.x;
      o1 = __builtin_fmaf(cs_o1, p, o1 + o0) * cx;
      o0 = (o0 + p) * hh.x;
    }
    if constexpr (DIR == 0) {   // alpha' = A * alpha_mid (absorbs leftover A^T)
      int rp = BPER(idx1, __float_as_int(o3));
      float p = ldexpf(__int_as_float(rp), dtl) * msk1;
      o3 = __builtin_fmaf(cs_o3, o1, o3 + o2);
      o2 = o2 + o1;
      o1 = __builtin_fmaf(cs_o1, p, o1 + o0);
      o0 = o0 + p;
    }
  }
  float* da = ws + SB_STATE + (size_t)(2 * b + DIR) * AREA;
  ((float4*)da)[l] = (float4){o0, o1, o2, o3};
  ((int*)da)[256 + l] = offs;
  if (l == 0) da[320] = msum;
}

// 512 threads = 8 independent waves per block = 4 batch elements (fwd+bwd each):
// 2 waves per SIMD -> stalls of one wave hide under the other's issue.
__global__ __launch_bounds__(512, 1) void k_alpha(const int* __restrict__ target,
                                                  const int* __restrict__ sizes,
                                                  const int* __restrict__ lablens,
                                                  float* __restrict__ ws) {
  __shared__ float ldsA[8 * 384];
  const int w = threadIdx.x >> 6;          // wave 0..7
  const int b = blockIdx.x * 4 + (w >> 1);
  const int dirw = w & 1;
  const int l = threadIdx.x & 63;
  float* exb = ldsA + w * 384;
  const int size = sizes[b];
  const float* recs_b = ws + REC_BASE + (size_t)b * TT * RECW;
  if (dirw == 0) run_chain<0>(target, lablens, recs_b, exb, size, b, l, ws);
  else           run_chain<1>(target, lablens, recs_b, exb, size, b, l, ws);
}

__global__ __launch_bounds__(64) void k_comb(float* __restrict__ ws) {
  const int b = blockIdx.x;
  const int l = threadIdx.x;
  const float* fa = ws + SB_STATE + (size_t)(2 * b) * AREA;
  const float* ba = fa + AREA;
  float4 av = ((const float4*)fa)[l];
  int eF = ((const int*)fa)[256 + l];
  float msF = fa[320], msB = ba[320];
  float pr0, pr1, pr2, pr3; int ex0, ex1, ex2, ex3, sb0, sb1, sb2, sb3;
#define CMP(k, AV, PR, EX, SBE) do {                                         \
    int s_ = 4 * l + (k);                                                    \
    int rho_ = 200 - s_;                                                     \
    int rc_ = (rho_ < 0) ? 0 : rho_;                                         \
    float g_ = ba[rc_];                                                      \
    int eB_ = ((const int*)ba)[256 + (rc_ >> 2)];                            \
    float p_ = (AV) * g_;                                                    \
    bool ok_ = (rho_ >= 0) && (p_ > 0.f);                                    \
    int eb_ = (int)((__float_as_uint(p_) >> 23) & 255u);                     \
    SBE = eF + eB_;                                                          \
    EX = ok_ ? (SBE + (eb_ ? eb_ - 127 : -140)) : (int)0xC0000000;           \
    PR = ok_ ? p_ : 0.f;                                                     \
  } while (0)
  CMP(0, av.x, pr0, ex0, sb0);
  CMP(1, av.y, pr1, ex1, sb1);
  CMP(2, av.z, pr2, ex2, sb2);
  CMP(3, av.w, pr3, ex3, sb3);
  int Em = ex0 > ex1 ? ex0 : ex1;
  Em = ex2 > Em ? ex2 : Em;
  Em = ex3 > Em ? ex3 : Em;
#pragma unroll
  for (int o = 32; o > 0; o >>= 1) {
    int t = __shfl_xor(Em, o, 64);
    Em = (t > Em) ? t : Em;
  }
  float v = 0.f;
#define ACC(PR, SBE) do { if (PR > 0.f) {                                    \
    int sh_ = SBE - Em; sh_ = sh_ < -300 ? -300 : (sh_ > 300 ? 300 : sh_);   \
    v += ldexpf(PR, sh_); } } while (0)
  ACC(pr0, sb0); ACC(pr1, sb1); ACC(pr2, sb2); ACC(pr3, sb3);
  float S = wave_sum64(v);
  if (l == 0) ws[b] = msF + msB + LN2 * ((float)Em + __builtin_log2f(S));
}

__global__ __launch_bounds__(64) void k_final(const float* __restrict__ ws, float* __restrict__ out) {
  float v = (threadIdx.x < BB) ? ws[threadIdx.x] : 0.0f;
  v = wave_sum64(v);
  if (threadIdx.x == 0) out[0] = -v;
}

extern "C" void kernel_launch(void* const* d_in, const int* in_sizes, int n_in,
                              void* d_out, int out_size, void* d_ws, size_t ws_size,
                              hipStream_t stream) {
  const float* acts  = (const float*)d_in[0];
  const int* target  = (const int*)d_in[1];
  const int* sizes   = (const int*)d_in[2];
  const int* lablens = (const int*)d_in[3];
  float* ws  = (float*)d_ws;
  float* out = (float*)d_out;
  const int nrec = TT * BB;
  k_gather<<<dim3(nrec / 4), dim3(256), 0, stream>>>(acts, target, ws);
  k_alpha<<<dim3(BB / 4), dim3(512), 0, stream>>>(target, sizes, lablens, ws);
  k_comb<<<dim3(BB), dim3(64), 0, stream>>>(ws);
  k_final<<<dim3(1), dim3(64), 0, stream>>>(ws, out);
}

// Round 18
// 125.195 us; speedup vs baseline: 1.2389x; 1.2389x over previous
//
#include <hip/hip_runtime.h>

// CTC forward loss, MI355X — fwd/bwd split (bwd = verified fwd machinery in
// reversed state coords rho=200-s, reversed labels). R18 (vs R16 base; R17's
// SMT-2 regressed — reverted):
//  * exchange bf16-packed: write 2 u32 + offs (12B/lane), read 2x2 u32 + 2 offs
//    (24B/lane) — cuts the DS-pipe RAW critical path ~40%.
//  * msk1-7 multiplies removed (redundant: masked ro -> d clamped -300 -> ~0).
//  * k_comb FUSED into k_alpha (results via LDS + __syncthreads, wave0 combines).
//  * records BF16-PACKED (56 f32/rec), triple-buffered global->reg prefetch.

#define TT 2000
#define BB 64
#define VV 128
#define LL 100
#define RECW 56
#define REC_BASE 256
#define NEGF (-1e30f)
#define L2E 1.44269504f
#define LN2 0.69314718f

__device__ __forceinline__ float wave_max64(float v) {
#pragma unroll
  for (int o = 32; o > 0; o >>= 1) v = fmaxf(v, __shfl_xor(v, o, 64));
  return v;
}
__device__ __forceinline__ float wave_sum64(float v) {
#pragma unroll
  for (int o = 32; o > 0; o >>= 1) v += __shfl_xor(v, o, 64);
  return v;
}
__device__ __forceinline__ float blo(unsigned u) { return __uint_as_float(u << 16); }
__device__ __forceinline__ float bhi(unsigned u) { return __uint_as_float(u & 0xFFFF0000u); }
__device__ __forceinline__ unsigned b16(float x) {
  unsigned b = __float_as_uint(x);
  return (b + 0x7FFFu + ((b >> 16) & 1u)) >> 16;   // RNE
}

__global__ __launch_bounds__(256) void k_gather(const float* __restrict__ acts,
                                                const int* __restrict__ target,
                                                float* __restrict__ ws) {
  const int lane = threadIdx.x & 63;
  const int w = threadIdx.x >> 6;
  const int r = blockIdx.x * 4 + w;          // r = t*BB + b
  if (r >= TT * BB) return;
  const int b = r % BB;
  const int t = r / BB;
  const float* row = acts + (size_t)r * VV;
  float x0 = row[lane];
  float x1 = row[lane + 64];
  float m = wave_max64(fmaxf(x0, x1));
  float e = __builtin_exp2f((x0 - m) * L2E) + __builtin_exp2f((x1 - m) * L2E);
  float s = wave_sum64(e);
  float lse = m + __builtin_log2f(s) * LN2;
  const int* lab = target + b * LL;
  const int j = lane;
  int ilo = (2 * j < 100) ? 2 * j : 99;
  int ihi = (2 * j + 1 < 100) ? 2 * j + 1 : 99;
  int cl = lab[ilo], ch = lab[ihi];
  float ya = __shfl(x0, cl & 63, 64), yb = __shfl(x1, cl & 63, 64);
  float ylo = (cl < 64) ? ya : yb;
  float yc = __shfl(x0, ch & 63, 64), yd = __shfl(x1, ch & 63, 64);
  float yhi = (ch < 64) ? yc : yd;
  float glo = (j < 50) ? (ylo - lse) : NEGF;
  float ghi = (j < 50) ? (yhi - lse) : NEGF;
  float gb = __shfl(x0, 0, 64) - lse;
  float gm = wave_max64(fmaxf(fmaxf(glo, ghi), gb));
  float qlo = __builtin_exp2f((glo - gm) * L2E);
  float qhi = __builtin_exp2f((ghi - gm) * L2E);
  unsigned u = b16(qlo) | (b16(qhi) << 16);
  unsigned* rec = (unsigned*)(ws + REC_BASE + ((size_t)b * TT + t) * RECW);
  if (j < 50) rec[2 + j] = u;
  if (j == 50) rec[52] = 0u;
  if (j == 0) {
    ((float*)rec)[0] = __builtin_exp2f((gb - gm) * L2E);
    ((float*)rec)[1] = gm;
  }
}

#define BPER __builtin_amdgcn_ds_bpermute
#define CL50(x) ((x) < 0 ? 0 : ((x) > 50 ? 50 : (x)))

// per-buffer: 4x h(float2) + 8x packed q + 1x packed aY = 17 regs
#define DECLR(P) float2 P##h0, P##h1, P##h2, P##h3; \
                 unsigned P##b0, P##b1, P##b2, P##b3, P##c0, P##c1, P##c2, P##c3, P##uA

// global->reg prefetch of one 4-step block (13 plain loads)
#define PREF(P, bidx) do {                                                   \
  int bi_ = (bidx); bi_ = (bi_ < bcap) ? bi_ : bcap; if (bi_ < 0) bi_ = 0;   \
  const float* r0_ = recs_b + (size_t)(tA + TS * 4 * bi_) * RECW;            \
  P##h0 = *(const float2*)(r0_);                                             \
  P##h1 = *(const float2*)(r0_ + TS * RECW);                                 \
  P##h2 = *(const float2*)(r0_ + TS * 2 * RECW);                             \
  P##h3 = *(const float2*)(r0_ + TS * 3 * RECW);                             \
  P##b0 = ((const unsigned*)r0_)[pbofs];                                     \
  P##c0 = ((const unsigned*)r0_)[pcofs];                                     \
  P##b1 = ((const unsigned*)(r0_ + TS * RECW))[pbofs];                       \
  P##c1 = ((const unsigned*)(r0_ + TS * RECW))[pcofs];                       \
  P##b2 = ((const unsigned*)(r0_ + TS * 2 * RECW))[pbofs];                   \
  P##c2 = ((const unsigned*)(r0_ + TS * 2 * RECW))[pcofs];                   \
  P##b3 = ((const unsigned*)(r0_ + TS * 3 * RECW))[pbofs];                   \
  P##c3 = ((const unsigned*)(r0_ + TS * 3 * RECW))[pcofs];                   \
  P##uA = ((const unsigned*)r0_)[payofs];                                    \
} while (0)

// top-down in-place update; NH = halo pairs updated (3/2/1/0)
#define STEP(qbv, gmv, cx, cy, bx, by, ay, NH) do {                          \
  const float qb_ = (qbv); msum += (gmv);                                    \
  o3 = __builtin_fmaf(cs_o3, o1, o3 + o2) * (cy);                            \
  o2 = (o2 + o1) * qb_;                                                      \
  o1 = __builtin_fmaf(cs_o1, h1, o1 + o0) * (cx);                            \
  o0 = (o0 + h1) * qb_;                                                      \
  if (NH >= 1) { h1 = __builtin_fmaf(cs_h1, h3, h1 + h2) * (by);             \
                 h2 = (h2 + h3) * qb_; }                                     \
  if (NH >= 2) { h3 = __builtin_fmaf(cs_h3, h5, h3 + h4) * (bx);             \
                 h4 = (h4 + h5) * qb_; }                                     \
  if (NH >= 3) { h5 = __builtin_fmaf(cs_h5, h7, h5 + h6) * (ay);             \
                 h6 = (h6 + h7) * qb_; }                                     \
} while (0)

// unpack to canonical (bx,by,cx,cy)
#define UQ(P, K, QV) float4 QV; do {                                         \
  if constexpr (DIR) {                                                       \
    QV = (float4){bhi(P##b##K), blo(P##b##K),                                \
                  bhi(P##c##K) * cmask, blo(P##c##K) * cmask};               \
  } else {                                                                   \
    QV = (float4){blo(P##b##K), bhi(P##b##K), blo(P##c##K), bhi(P##c##K)};   \
  }                                                                          \
} while (0)

// 4 steps + exchange WRITE (bf16-packed: 2 u32 values + offs)
#define COMPA(P) do {                                                        \
  UQ(P, 0, q0_); UQ(P, 1, q1_); UQ(P, 2, q2_); UQ(P, 3, q3_);                \
  float aYv = DIR ? blo(P##uA) : bhi(P##uA);                                 \
  STEP(P##h0.x, P##h0.y, q0_.z, q0_.w, q0_.x, q0_.y, aYv, 3);                \
  STEP(P##h1.x, P##h1.y, q1_.z, q1_.w, q1_.x, q1_.y, 0.f, 2);                \
  STEP(P##h2.x, P##h2.y, q2_.z, q2_.w, q2_.x, q2_.y, 0.f, 1);                \
  STEP(P##h3.x, P##h3.y, q3_.z, q3_.w, 0.f, 0.f, 0.f, 0);                    \
  unsigned p01_ = b16(o0) | (b16(o1) << 16);                                 \
  unsigned p23_ = b16(o2) | (b16(o3) << 16);                                 \
  *(uint2*)(exbU + 2 * l) = (uint2){p01_, p23_};                             \
  exbU[128 + l] = (unsigned)offs;                                            \
} while (0)

// exchange READ + reconcile (bf16 halos; own states stay f32)
#define FINL() do {                                                          \
  asm volatile("" ::: "memory");                                             \
  uint2 W1_ = *(const uint2*)(exbU + 2 * ((l >= 1) ? (l - 1) : 0));          \
  uint2 W2_ = *(const uint2*)(exbU + 2 * ((l >= 2) ? (l - 2) : 0));          \
  int ro1_ = (int)exbU[128 + ((l >= 1) ? (l - 1) : 0)];                      \
  int ro2_ = (int)exbU[128 + ((l >= 2) ? (l - 2) : 0)];                      \
  ro1_ = (l >= 1) ? ro1_ : -(1 << 29);                                       \
  ro2_ = (l >= 2) ? ro2_ : -(1 << 29);                                       \
  float m_ = fmaxf(fmaxf(o0, o1), fmaxf(o2, o3));                            \
  int eb_ = (int)((__float_as_uint(m_) >> 23) & 255u);                       \
  int t1_ = offs + (eb_ ? (eb_ - 127) : -126);                               \
  int mx_ = (ro1_ > ro2_) ? ro1_ : ro2_;                                     \
  int onew_ = (t1_ > mx_) ? t1_ : mx_;                                       \
  int ds_ = offs - onew_;  ds_ = (ds_ < -300) ? -300 : ds_;                  \
  int d1_ = ro1_ - onew_, d2_ = ro2_ - onew_;                                \
  d1_ = (d1_ < -300) ? -300 : d1_;                                           \
  d2_ = (d2_ < -300) ? -300 : d2_;                                           \
  o0 = ldexpf(o0, ds_); o1 = ldexpf(o1, ds_);                                \
  o2 = ldexpf(o2, ds_); o3 = ldexpf(o3, ds_);                                \
  h1 = ldexpf(bhi(W1_.y), d1_);                                              \
  h2 = ldexpf(blo(W1_.y), d1_);                                              \
  h3 = ldexpf(bhi(W1_.x), d1_);                                              \
  h4 = ldexpf(blo(W1_.x), d1_);                                              \
  h5 = ldexpf(bhi(W2_.y), d2_);                                              \
  h6 = ldexpf(blo(W2_.y), d2_);                                              \
  h7 = ldexpf(bhi(W2_.x), d2_);                                              \
  offs = onew_;                                                              \
} while (0)

template <int DIR>
__device__ __forceinline__ void run_chain(const int* __restrict__ target,
                                          const int* __restrict__ lablens,
                                          const float* __restrict__ recs_b,
                                          float* exb, int size, int b, int l) {
  unsigned* exbU = (unsigned*)exb;
  const int mid = (size - 1) >> 1;
  const int sizeP = DIR ? (size - 1 - mid) : (mid + 1);
  const int* lab = target + b * LL;
  const int lc = (l < 50) ? l : 50;
  const int tA = DIR ? (size - 2) : 1;
  constexpr int TS = DIR ? -1 : 1;
  const int bcap = DIR ? ((size - 5) >> 2) : 498;
  const int pbofs = 2 + (DIR ? CL50(50 - l) : CL50(l - 1));
  const int pcofs = 2 + (DIR ? CL50(49 - l) : CL50(l));
  const int payofs = 2 + (DIR ? CL50(51 - l) : CL50(l - 2));
  const float cmask = (l < 50) ? 1.f : 0.f;
  const int idx1 = ((l + 63) & 63) << 2;
  const float msk1 = (4 * l - 1 >= 0) ? 1.f : 0.f;   // tail only
  // skip masks: fwd from lab ascending; bwd from reversed labels lab'[j]=lab[99-j]
  int i0, i1, i2, i3, i4, i5;
  if constexpr (DIR == 0) { i0 = 2*l+1; i1 = 2*l; i2 = 2*l-1; i3 = 2*l-2; i4 = 2*l-3; i5 = 2*l-4; }
  else { i0 = 98-2*l; i1 = 99-2*l; i2 = 100-2*l; i3 = 101-2*l; i4 = 102-2*l; i5 = 103-2*l; }
#define CLM(x) ((x) < 0 ? 0 : ((x) > 99 ? 99 : (x)))
  const int La = lab[CLM(i0)], Lb_ = lab[CLM(i1)], Lc = lab[CLM(i2)];
  const int Ld = lab[CLM(i3)], Le = lab[CLM(i4)], Lf = lab[CLM(i5)];
  const float cs_o3 = (La != Lb_) ? 1.f : 0.f;
  const float cs_o1 = (Lb_ != Lc) ? 1.f : 0.f;
  const float cs_h1 = (Lc != Ld) ? 1.f : 0.f;
  const float cs_h3 = (Ld != Le) ? 1.f : 0.f;
  const float cs_h5 = (Le != Lf) ? 1.f : 0.f;
  // init
  float o0 = 0.f, o1 = 0.f, o2 = 0.f, o3 = 0.f;
  float h1 = 0.f, h2 = 0.f, h3 = 0.f, h4 = 0.f, h5 = 0.f, h6 = 0.f, h7 = 0.f;
  int offs = 0;
  float msum;
  if constexpr (DIR == 0) {
    msum = recs_b[1];
    float q0i = blo(((const unsigned*)recs_b)[2]);   // q_lab[0]
    if (l == 0) { o0 = recs_b[0]; o1 = q0i; }
    if (l == 1) { h3 = q0i; h4 = recs_b[0]; }
    if (l == 2) { h7 = q0i; }
  } else {
    const float* recL = recs_b + (size_t)(size - 1) * RECW;
    msum = recL[1];
    const int Lbv = lablens[b];
    const int r0v = 200 - 2 * Lbv;   // rho of end state 2L; r0v+1 = rho of 2L-1
    auto gi = [&](int rho) -> float {
      if (rho != r0v && rho != r0v + 1) return 0.f;
      if ((rho & 1) == 0) return recL[0];
      int mm = 99 - ((rho - 1) >> 1);
      unsigned u = ((const unsigned*)recL)[2 + (mm >> 1)];
      return (mm & 1) ? bhi(u) : blo(u);
    };
    o0 = gi(4*l); o1 = gi(4*l+1); o2 = gi(4*l+2); o3 = gi(4*l+3);
    h1 = gi(4*l-1); h2 = gi(4*l-2); h3 = gi(4*l-3); h4 = gi(4*l-4);
    h5 = gi(4*l-5); h6 = gi(4*l-6); h7 = gi(4*l-7);
  }

  const int nb = (sizeP - 1) >> 2;
  DECLR(A); DECLR(B); DECLR(C);
  PREF(A, 0); PREF(B, 1);
  int blk = 0;
  for (; blk + 3 <= nb; blk += 3) {
    COMPA(A); PREF(C, blk + 2); FINL();
    COMPA(B); PREF(A, blk + 3); FINL();
    COMPA(C); PREF(B, blk + 4); FINL();
  }
  if (nb - blk >= 1) { COMPA(A); FINL(); }
  if (nb - blk >= 2) { COMPA(B); FINL(); }
  // tail (<=3 steps) + forward-only extra A-step
  {
    int rno1 = BPER(idx1, offs);
    int dtl = rno1 - offs;
    dtl = (dtl > 120) ? 120 : ((dtl < -300) ? -300 : dtl);
    for (int tau = 1 + 4 * nb; tau < sizeP; ++tau) {
      const float* rt = recs_b + (size_t)(DIR ? (size - 1 - tau) : tau) * RECW;
      float2 hh = *(const float2*)rt;
      float cx, cy;
      if constexpr (DIR == 0) {
        unsigned u = ((const unsigned*)rt)[2 + lc];   // pair lc (lc=50 -> zero pad)
        cx = blo(u); cy = bhi(u);
      } else {
        unsigned u = ((const unsigned*)rt)[2 + CL50(50 - l)];
        cx = bhi(u) * cmask; cy = blo(u) * cmask;
      }
      int rp = BPER(idx1, __float_as_int(o3));
      float p = ldexpf(__int_as_float(rp), dtl) * msk1;
      msum += hh.y;
      o3 = __builtin_fmaf(cs_o3, o1, o3 + o2) * cy;
      o2 = (o2 + o1) * hh.x;
      o1 = __builtin_fmaf(cs_o1, p, o1 + o0) * cx;
      o0 = (o0 + p) * hh.x;
    }
    if constexpr (DIR == 0) {   // alpha' = A * alpha_mid (absorbs leftover A^T)
      int rp = BPER(idx1, __float_as_int(o3));
      float p = ldexpf(__int_as_float(rp), dtl) * msk1;
      o3 = __builtin_fmaf(cs_o3, o1, o3 + o2);
      o2 = o2 + o1;
      o1 = __builtin_fmaf(cs_o1, p, o1 + o0);
      o0 = o0 + p;
    }
  }
  // results -> LDS (exchange region is dead now): vals[256], offs[64], msum
  asm volatile("" ::: "memory");
  ((float4*)exb)[l] = (float4){o0, o1, o2, o3};
  ((int*)exb)[256 + l] = offs;
  if (l == 0) exb[320] = msum;
}

// 128 threads = 2 independent waves (fwd, bwd of same b) + fused combine.
__global__ __launch_bounds__(128, 1) void k_alpha(const int* __restrict__ target,
                                                  const int* __restrict__ sizes,
                                                  const int* __restrict__ lablens,
                                                  float* __restrict__ ws) {
  __shared__ float ldsA[2 * 384];
  const int b = blockIdx.x;
  const int dirw = threadIdx.x >> 6;
  const int l = threadIdx.x & 63;
  float* exb = ldsA + dirw * 384;
  const int size = sizes[b];
  const float* recs_b = ws + REC_BASE + (size_t)b * TT * RECW;
  if (dirw == 0) run_chain<0>(target, lablens, recs_b, exb, size, b, l);
  else           run_chain<1>(target, lablens, recs_b, exb, size, b, l);
  __syncthreads();
  if (dirw == 0) {
    const float* fa = ldsA;
    const float* ba = ldsA + 384;
    float4 av = ((const float4*)fa)[l];
    int eF = ((const int*)fa)[256 + l];
    float msF = fa[320], msB = ba[320];
    float pr0, pr1, pr2, pr3; int ex0, ex1, ex2, ex3, sb0, sb1, sb2, sb3;
#define CMP(k, AV, PR, EX, SBE) do {                                         \
      int s_ = 4 * l + (k);                                                  \
      int rho_ = 200 - s_;                                                   \
      int rc_ = (rho_ < 0) ? 0 : rho_;                                       \
      float g_ = ba[rc_];                                                    \
      int eB_ = ((const int*)ba)[256 + (rc_ >> 2)];                          \
      float p_ = (AV) * g_;                                                  \
      bool ok_ = (rho_ >= 0) && (p_ > 0.f);                                  \
      int eb_ = (int)((__float_as_uint(p_) >> 23) & 255u);                   \
      SBE = eF + eB_;                                                        \
      EX = ok_ ? (SBE + (eb_ ? eb_ - 127 : -140)) : (int)0xC0000000;         \
      PR = ok_ ? p_ : 0.f;                                                   \
    } while (0)
    CMP(0, av.x, pr0, ex0, sb0);
    CMP(1, av.y, pr1, ex1, sb1);
    CMP(2, av.z, pr2, ex2, sb2);
    CMP(3, av.w, pr3, ex3, sb3);
    int Em = ex0 > ex1 ? ex0 : ex1;
    Em = ex2 > Em ? ex2 : Em;
    Em = ex3 > Em ? ex3 : Em;
#pragma unroll
    for (int o = 32; o > 0; o >>= 1) {
      int t = __shfl_xor(Em, o, 64);
      Em = (t > Em) ? t : Em;
    }
    float v = 0.f;
#define ACC(PR, SBE) do { if (PR > 0.f) {                                    \
      int sh_ = SBE - Em; sh_ = sh_ < -300 ? -300 : (sh_ > 300 ? 300 : sh_); \
      v += ldexpf(PR, sh_); } } while (0)
    ACC(pr0, sb0); ACC(pr1, sb1); ACC(pr2, sb2); ACC(pr3, sb3);
    float S = wave_sum64(v);
    if (l == 0) ws[b] = msF + msB + LN2 * ((float)Em + __builtin_log2f(S));
  }
}

__global__ __launch_bounds__(64) void k_final(const float* __restrict__ ws, float* __restrict__ out) {
  float v = (threadIdx.x < BB) ? ws[threadIdx.x] : 0.0f;
  v = wave_sum64(v);
  if (threadIdx.x == 0) out[0] = -v;
}

extern "C" void kernel_launch(void* const* d_in, const int* in_sizes, int n_in,
                              void* d_out, int out_size, void* d_ws, size_t ws_size,
                              hipStream_t stream) {
  const float* acts  = (const float*)d_in[0];
  const int* target  = (const int*)d_in[1];
  const int* sizes   = (const int*)d_in[2];
  const int* lablens = (const int*)d_in[3];
  float* ws  = (float*)d_ws;
  float* out = (float*)d_out;
  const int nrec = TT * BB;
  k_gather<<<dim3(nrec / 4), dim3(256), 0, stream>>>(acts, target, ws);
  k_alpha<<<dim3(BB), dim3(128), 0, stream>>>(target, sizes, lablens, ws);
  k_final<<<dim3(1), dim3(64), 0, stream>>>(ws, out);
}

// Round 19
// 124.734 us; speedup vs baseline: 1.2435x; 1.0037x over previous
//
#include <hip/hip_runtime.h>

// CTC forward loss, MI355X — fwd/bwd split (bwd = verified fwd machinery in
// reversed state coords rho=200-s, reversed labels). R19 (vs R18):
//  * PIN(P): empty inline-asm "+v" on all buffer values, placed ONE sub-iter
//    after PREF(P) (completion naturally done -> no stall at pin) and one
//    before COMPA(P). Prevents the allocator from sinking PREF's loads to
//    point-of-use (R16/R18 VGPR=52 proves buffers weren't held; ~200cyc L2
//    latency exposed per sub-iter). Loads stay compiler-managed (no vmcnt asm).
//  * records BF16-PACKED (56 f32/rec); bf16-packed LDS exchange; fused combine.

#define TT 2000
#define BB 64
#define VV 128
#define LL 100
#define RECW 56
#define REC_BASE 256
#define NEGF (-1e30f)
#define L2E 1.44269504f
#define LN2 0.69314718f

__device__ __forceinline__ float wave_max64(float v) {
#pragma unroll
  for (int o = 32; o > 0; o >>= 1) v = fmaxf(v, __shfl_xor(v, o, 64));
  return v;
}
__device__ __forceinline__ float wave_sum64(float v) {
#pragma unroll
  for (int o = 32; o > 0; o >>= 1) v += __shfl_xor(v, o, 64);
  return v;
}
__device__ __forceinline__ float blo(unsigned u) { return __uint_as_float(u << 16); }
__device__ __forceinline__ float bhi(unsigned u) { return __uint_as_float(u & 0xFFFF0000u); }
__device__ __forceinline__ unsigned b16(float x) {
  unsigned b = __float_as_uint(x);
  return (b + 0x7FFFu + ((b >> 16) & 1u)) >> 16;   // RNE
}

__global__ __launch_bounds__(256) void k_gather(const float* __restrict__ acts,
                                                const int* __restrict__ target,
                                                float* __restrict__ ws) {
  const int lane = threadIdx.x & 63;
  const int w = threadIdx.x >> 6;
  const int r = blockIdx.x * 4 + w;          // r = t*BB + b
  if (r >= TT * BB) return;
  const int b = r % BB;
  const int t = r / BB;
  const float* row = acts + (size_t)r * VV;
  float x0 = row[lane];
  float x1 = row[lane + 64];
  float m = wave_max64(fmaxf(x0, x1));
  float e = __builtin_exp2f((x0 - m) * L2E) + __builtin_exp2f((x1 - m) * L2E);
  float s = wave_sum64(e);
  float lse = m + __builtin_log2f(s) * LN2;
  const int* lab = target + b * LL;
  const int j = lane;
  int ilo = (2 * j < 100) ? 2 * j : 99;
  int ihi = (2 * j + 1 < 100) ? 2 * j + 1 : 99;
  int cl = lab[ilo], ch = lab[ihi];
  float ya = __shfl(x0, cl & 63, 64), yb = __shfl(x1, cl & 63, 64);
  float ylo = (cl < 64) ? ya : yb;
  float yc = __shfl(x0, ch & 63, 64), yd = __shfl(x1, ch & 63, 64);
  float yhi = (ch < 64) ? yc : yd;
  float glo = (j < 50) ? (ylo - lse) : NEGF;
  float ghi = (j < 50) ? (yhi - lse) : NEGF;
  float gb = __shfl(x0, 0, 64) - lse;
  float gm = wave_max64(fmaxf(fmaxf(glo, ghi), gb));
  float qlo = __builtin_exp2f((glo - gm) * L2E);
  float qhi = __builtin_exp2f((ghi - gm) * L2E);
  unsigned u = b16(qlo) | (b16(qhi) << 16);
  unsigned* rec = (unsigned*)(ws + REC_BASE + ((size_t)b * TT + t) * RECW);
  if (j < 50) rec[2 + j] = u;
  if (j == 50) rec[52] = 0u;
  if (j == 0) {
    ((float*)rec)[0] = __builtin_exp2f((gb - gm) * L2E);
    ((float*)rec)[1] = gm;
  }
}

#define BPER __builtin_amdgcn_ds_bpermute
#define CL50(x) ((x) < 0 ? 0 : ((x) > 50 ? 50 : (x)))

// per-buffer: 4x h(float2) + 8x packed q + 1x packed aY = 17 regs
#define DECLR(P) float2 P##h0, P##h1, P##h2, P##h3; \
                 unsigned P##b0, P##b1, P##b2, P##b3, P##c0, P##c1, P##c2, P##c3, P##uA

// residency pin: forbids sinking P's loads past this point (values must be in
// VGPRs here). Placed where completion is naturally done -> no stall.
#define PIN(P) asm volatile("" : "+v"(P##h0), "+v"(P##h1), "+v"(P##h2),      \
  "+v"(P##h3), "+v"(P##b0), "+v"(P##b1), "+v"(P##b2), "+v"(P##b3),           \
  "+v"(P##c0), "+v"(P##c1), "+v"(P##c2), "+v"(P##c3), "+v"(P##uA))

// global->reg prefetch of one 4-step block (13 plain loads)
#define PREF(P, bidx) do {                                                   \
  int bi_ = (bidx); bi_ = (bi_ < bcap) ? bi_ : bcap; if (bi_ < 0) bi_ = 0;   \
  const float* r0_ = recs_b + (size_t)(tA + TS * 4 * bi_) * RECW;            \
  P##h0 = *(const float2*)(r0_);                                             \
  P##h1 = *(const float2*)(r0_ + TS * RECW);                                 \
  P##h2 = *(const float2*)(r0_ + TS * 2 * RECW);                             \
  P##h3 = *(const float2*)(r0_ + TS * 3 * RECW);                             \
  P##b0 = ((const unsigned*)r0_)[pbofs];                                     \
  P##c0 = ((const unsigned*)r0_)[pcofs];                                     \
  P##b1 = ((const unsigned*)(r0_ + TS * RECW))[pbofs];                       \
  P##c1 = ((const unsigned*)(r0_ + TS * RECW))[pcofs];                       \
  P##b2 = ((const unsigned*)(r0_ + TS * 2 * RECW))[pbofs];                   \
  P##c2 = ((const unsigned*)(r0_ + TS * 2 * RECW))[pcofs];                   \
  P##b3 = ((const unsigned*)(r0_ + TS * 3 * RECW))[pbofs];                   \
  P##c3 = ((const unsigned*)(r0_ + TS * 3 * RECW))[pcofs];                   \
  P##uA = ((const unsigned*)r0_)[payofs];                                    \
} while (0)

// top-down in-place update; NH = halo pairs updated (3/2/1/0)
#define STEP(qbv, gmv, cx, cy, bx, by, ay, NH) do {                          \
  const float qb_ = (qbv); msum += (gmv);                                    \
  o3 = __builtin_fmaf(cs_o3, o1, o3 + o2) * (cy);                            \
  o2 = (o2 + o1) * qb_;                                                      \
  o1 = __builtin_fmaf(cs_o1, h1, o1 + o0) * (cx);                            \
  o0 = (o0 + h1) * qb_;                                                      \
  if (NH >= 1) { h1 = __builtin_fmaf(cs_h1, h3, h1 + h2) * (by);             \
                 h2 = (h2 + h3) * qb_; }                                     \
  if (NH >= 2) { h3 = __builtin_fmaf(cs_h3, h5, h3 + h4) * (bx);             \
                 h4 = (h4 + h5) * qb_; }                                     \
  if (NH >= 3) { h5 = __builtin_fmaf(cs_h5, h7, h5 + h6) * (ay);             \
                 h6 = (h6 + h7) * qb_; }                                     \
} while (0)

// unpack to canonical (bx,by,cx,cy)
#define UQ(P, K, QV) float4 QV; do {                                         \
  if constexpr (DIR) {                                                       \
    QV = (float4){bhi(P##b##K), blo(P##b##K),                                \
                  bhi(P##c##K) * cmask, blo(P##c##K) * cmask};               \
  } else {                                                                   \
    QV = (float4){blo(P##b##K), bhi(P##b##K), blo(P##c##K), bhi(P##c##K)};   \
  }                                                                          \
} while (0)

// 4 steps + exchange WRITE (bf16-packed: 2 u32 values + offs)
#define COMPA(P) do {                                                        \
  UQ(P, 0, q0_); UQ(P, 1, q1_); UQ(P, 2, q2_); UQ(P, 3, q3_);                \
  float aYv = DIR ? blo(P##uA) : bhi(P##uA);                                 \
  STEP(P##h0.x, P##h0.y, q0_.z, q0_.w, q0_.x, q0_.y, aYv, 3);                \
  STEP(P##h1.x, P##h1.y, q1_.z, q1_.w, q1_.x, q1_.y, 0.f, 2);                \
  STEP(P##h2.x, P##h2.y, q2_.z, q2_.w, q2_.x, q2_.y, 0.f, 1);                \
  STEP(P##h3.x, P##h3.y, q3_.z, q3_.w, 0.f, 0.f, 0.f, 0);                    \
  unsigned p01_ = b16(o0) | (b16(o1) << 16);                                 \
  unsigned p23_ = b16(o2) | (b16(o3) << 16);                                 \
  *(uint2*)(exbU + 2 * l) = (uint2){p01_, p23_};                             \
  exbU[128 + l] = (unsigned)offs;                                            \
} while (0)

// exchange READ + reconcile (bf16 halos; own states stay f32)
#define FINL() do {                                                          \
  asm volatile("" ::: "memory");                                             \
  uint2 W1_ = *(const uint2*)(exbU + 2 * ((l >= 1) ? (l - 1) : 0));          \
  uint2 W2_ = *(const uint2*)(exbU + 2 * ((l >= 2) ? (l - 2) : 0));          \
  int ro1_ = (int)exbU[128 + ((l >= 1) ? (l - 1) : 0)];                      \
  int ro2_ = (int)exbU[128 + ((l >= 2) ? (l - 2) : 0)];                      \
  ro1_ = (l >= 1) ? ro1_ : -(1 << 29);                                       \
  ro2_ = (l >= 2) ? ro2_ : -(1 << 29);                                       \
  float m_ = fmaxf(fmaxf(o0, o1), fmaxf(o2, o3));                            \
  int eb_ = (int)((__float_as_uint(m_) >> 23) & 255u);                       \
  int t1_ = offs + (eb_ ? (eb_ - 127) : -126);                               \
  int mx_ = (ro1_ > ro2_) ? ro1_ : ro2_;                                     \
  int onew_ = (t1_ > mx_) ? t1_ : mx_;                                       \
  int ds_ = offs - onew_;  ds_ = (ds_ < -300) ? -300 : ds_;                  \
  int d1_ = ro1_ - onew_, d2_ = ro2_ - onew_;                                \
  d1_ = (d1_ < -300) ? -300 : d1_;                                           \
  d2_ = (d2_ < -300) ? -300 : d2_;                                           \
  o0 = ldexpf(o0, ds_); o1 = ldexpf(o1, ds_);                                \
  o2 = ldexpf(o2, ds_); o3 = ldexpf(o3, ds_);                                \
  h1 = ldexpf(bhi(W1_.y), d1_);                                              \
  h2 = ldexpf(blo(W1_.y), d1_);                                              \
  h3 = ldexpf(bhi(W1_.x), d1_);                                              \
  h4 = ldexpf(blo(W1_.x), d1_);                                              \
  h5 = ldexpf(bhi(W2_.y), d2_);                                              \
  h6 = ldexpf(blo(W2_.y), d2_);                                              \
  h7 = ldexpf(bhi(W2_.x), d2_);                                              \
  offs = onew_;                                                              \
} while (0)

template <int DIR>
__device__ __forceinline__ void run_chain(const int* __restrict__ target,
                                          const int* __restrict__ lablens,
                                          const float* __restrict__ recs_b,
                                          float* exb, int size, int b, int l) {
  unsigned* exbU = (unsigned*)exb;
  const int mid = (size - 1) >> 1;
  const int sizeP = DIR ? (size - 1 - mid) : (mid + 1);
  const int* lab = target + b * LL;
  const int lc = (l < 50) ? l : 50;
  const int tA = DIR ? (size - 2) : 1;
  constexpr int TS = DIR ? -1 : 1;
  const int bcap = DIR ? ((size - 5) >> 2) : 498;
  const int pbofs = 2 + (DIR ? CL50(50 - l) : CL50(l - 1));
  const int pcofs = 2 + (DIR ? CL50(49 - l) : CL50(l));
  const int payofs = 2 + (DIR ? CL50(51 - l) : CL50(l - 2));
  const float cmask = (l < 50) ? 1.f : 0.f;
  const int idx1 = ((l + 63) & 63) << 2;
  const float msk1 = (4 * l - 1 >= 0) ? 1.f : 0.f;   // tail only
  // skip masks: fwd from lab ascending; bwd from reversed labels lab'[j]=lab[99-j]
  int i0, i1, i2, i3, i4, i5;
  if constexpr (DIR == 0) { i0 = 2*l+1; i1 = 2*l; i2 = 2*l-1; i3 = 2*l-2; i4 = 2*l-3; i5 = 2*l-4; }
  else { i0 = 98-2*l; i1 = 99-2*l; i2 = 100-2*l; i3 = 101-2*l; i4 = 102-2*l; i5 = 103-2*l; }
#define CLM(x) ((x) < 0 ? 0 : ((x) > 99 ? 99 : (x)))
  const int La = lab[CLM(i0)], Lb_ = lab[CLM(i1)], Lc = lab[CLM(i2)];
  const int Ld = lab[CLM(i3)], Le = lab[CLM(i4)], Lf = lab[CLM(i5)];
  const float cs_o3 = (La != Lb_) ? 1.f : 0.f;
  const float cs_o1 = (Lb_ != Lc) ? 1.f : 0.f;
  const float cs_h1 = (Lc != Ld) ? 1.f : 0.f;
  const float cs_h3 = (Ld != Le) ? 1.f : 0.f;
  const float cs_h5 = (Le != Lf) ? 1.f : 0.f;
  // init
  float o0 = 0.f, o1 = 0.f, o2 = 0.f, o3 = 0.f;
  float h1 = 0.f, h2 = 0.f, h3 = 0.f, h4 = 0.f, h5 = 0.f, h6 = 0.f, h7 = 0.f;
  int offs = 0;
  float msum;
  if constexpr (DIR == 0) {
    msum = recs_b[1];
    float q0i = blo(((const unsigned*)recs_b)[2]);   // q_lab[0]
    if (l == 0) { o0 = recs_b[0]; o1 = q0i; }
    if (l == 1) { h3 = q0i; h4 = recs_b[0]; }
    if (l == 2) { h7 = q0i; }
  } else {
    const float* recL = recs_b + (size_t)(size - 1) * RECW;
    msum = recL[1];
    const int Lbv = lablens[b];
    const int r0v = 200 - 2 * Lbv;   // rho of end state 2L; r0v+1 = rho of 2L-1
    auto gi = [&](int rho) -> float {
      if (rho != r0v && rho != r0v + 1) return 0.f;
      if ((rho & 1) == 0) return recL[0];
      int mm = 99 - ((rho - 1) >> 1);
      unsigned u = ((const unsigned*)recL)[2 + (mm >> 1)];
      return (mm & 1) ? bhi(u) : blo(u);
    };
    o0 = gi(4*l); o1 = gi(4*l+1); o2 = gi(4*l+2); o3 = gi(4*l+3);
    h1 = gi(4*l-1); h2 = gi(4*l-2); h3 = gi(4*l-3); h4 = gi(4*l-4);
    h5 = gi(4*l-5); h6 = gi(4*l-6); h7 = gi(4*l-7);
  }

  const int nb = (sizeP - 1) >> 2;
  DECLR(A); DECLR(B); DECLR(C);
  PREF(A, 0); PREF(B, 1);
  int blk = 0;
  for (; blk + 3 <= nb; blk += 3) {
    COMPA(A); PREF(C, blk + 2); FINL(); PIN(B);
    COMPA(B); PREF(A, blk + 3); FINL(); PIN(C);
    COMPA(C); PREF(B, blk + 4); FINL(); PIN(A);
  }
  if (nb - blk >= 1) { COMPA(A); FINL(); }
  if (nb - blk >= 2) { COMPA(B); FINL(); }
  // tail (<=3 steps) + forward-only extra A-step
  {
    int rno1 = BPER(idx1, offs);
    int dtl = rno1 - offs;
    dtl = (dtl > 120) ? 120 : ((dtl < -300) ? -300 : dtl);
    for (int tau = 1 + 4 * nb; tau < sizeP; ++tau) {
      const float* rt = recs_b + (size_t)(DIR ? (size - 1 - tau) : tau) * RECW;
      float2 hh = *(const float2*)rt;
      float cx, cy;
      if constexpr (DIR == 0) {
        unsigned u = ((const unsigned*)rt)[2 + lc];   // pair lc (lc=50 -> zero pad)
        cx = blo(u); cy = bhi(u);
      } else {
        unsigned u = ((const unsigned*)rt)[2 + CL50(50 - l)];
        cx = bhi(u) * cmask; cy = blo(u) * cmask;
      }
      int rp = BPER(idx1, __float_as_int(o3));
      float p = ldexpf(__int_as_float(rp), dtl) * msk1;
      msum += hh.y;
      o3 = __builtin_fmaf(cs_o3, o1, o3 + o2) * cy;
      o2 = (o2 + o1) * hh.x;
      o1 = __builtin_fmaf(cs_o1, p, o1 + o0) * cx;
      o0 = (o0 + p) * hh.x;
    }
    if constexpr (DIR == 0) {   // alpha' = A * alpha_mid (absorbs leftover A^T)
      int rp = BPER(idx1, __float_as_int(o3));
      float p = ldexpf(__int_as_float(rp), dtl) * msk1;
      o3 = __builtin_fmaf(cs_o3, o1, o3 + o2);
      o2 = o2 + o1;
      o1 = __builtin_fmaf(cs_o1, p, o1 + o0);
      o0 = o0 + p;
    }
  }
  // results -> LDS (exchange region is dead now): vals[256], offs[64], msum
  asm volatile("" ::: "memory");
  ((float4*)exb)[l] = (float4){o0, o1, o2, o3};
  ((int*)exb)[256 + l] = offs;
  if (l == 0) exb[320] = msum;
}

// 128 threads = 2 independent waves (fwd, bwd of same b) + fused combine.
__global__ __launch_bounds__(128, 1) void k_alpha(const int* __restrict__ target,
                                                  const int* __restrict__ sizes,
                                                  const int* __restrict__ lablens,
                                                  float* __restrict__ ws) {
  __shared__ float ldsA[2 * 384];
  const int b = blockIdx.x;
  const int dirw = threadIdx.x >> 6;
  const int l = threadIdx.x & 63;
  float* exb = ldsA + dirw * 384;
  const int size = sizes[b];
  const float* recs_b = ws + REC_BASE + (size_t)b * TT * RECW;
  if (dirw == 0) run_chain<0>(target, lablens, recs_b, exb, size, b, l);
  else           run_chain<1>(target, lablens, recs_b, exb, size, b, l);
  __syncthreads();
  if (dirw == 0) {
    const float* fa = ldsA;
    const float* ba = ldsA + 384;
    float4 av = ((const float4*)fa)[l];
    int eF = ((const int*)fa)[256 + l];
    float msF = fa[320], msB = ba[320];
    float pr0, pr1, pr2, pr3; int ex0, ex1, ex2, ex3, sb0, sb1, sb2, sb3;
#define CMP(k, AV, PR, EX, SBE) do {                                         \
      int s_ = 4 * l + (k);                                                  \
      int rho_ = 200 - s_;                                                   \
      int rc_ = (rho_ < 0) ? 0 : rho_;                                       \
      float g_ = ba[rc_];                                                    \
      int eB_ = ((const int*)ba)[256 + (rc_ >> 2)];                          \
      float p_ = (AV) * g_;                                                  \
      bool ok_ = (rho_ >= 0) && (p_ > 0.f);                                  \
      int eb_ = (int)((__float_as_uint(p_) >> 23) & 255u);                   \
      SBE = eF + eB_;                                                        \
      EX = ok_ ? (SBE + (eb_ ? eb_ - 127 : -140)) : (int)0xC0000000;         \
      PR = ok_ ? p_ : 0.f;                                                   \
    } while (0)
    CMP(0, av.x, pr0, ex0, sb0);
    CMP(1, av.y, pr1, ex1, sb1);
    CMP(2, av.z, pr2, ex2, sb2);
    CMP(3, av.w, pr3, ex3, sb3);
    int Em = ex0 > ex1 ? ex0 : ex1;
    Em = ex2 > Em ? ex2 : Em;
    Em = ex3 > Em ? ex3 : Em;
#pragma unroll
    for (int o = 32; o > 0; o >>= 1) {
      int t = __shfl_xor(Em, o, 64);
      Em = (t > Em) ? t : Em;
    }
    float v = 0.f;
#define ACC(PR, SBE) do { if (PR > 0.f) {                                    \
      int sh_ = SBE - Em; sh_ = sh_ < -300 ? -300 : (sh_ > 300 ? 300 : sh_); \
      v += ldexpf(PR, sh_); } } while (0)
    ACC(pr0, sb0); ACC(pr1, sb1); ACC(pr2, sb2); ACC(pr3, sb3);
    float S = wave_sum64(v);
    if (l == 0) ws[b] = msF + msB + LN2 * ((float)Em + __builtin_log2f(S));
  }
}

__global__ __launch_bounds__(64) void k_final(const float* __restrict__ ws, float* __restrict__ out) {
  float v = (threadIdx.x < BB) ? ws[threadIdx.x] : 0.0f;
  v = wave_sum64(v);
  if (threadIdx.x == 0) out[0] = -v;
}

extern "C" void kernel_launch(void* const* d_in, const int* in_sizes, int n_in,
                              void* d_out, int out_size, void* d_ws, size_t ws_size,
                              hipStream_t stream) {
  const float* acts  = (const float*)d_in[0];
  const int* target  = (const int*)d_in[1];
  const int* sizes   = (const int*)d_in[2];
  const int* lablens = (const int*)d_in[3];
  float* ws  = (float*)d_ws;
  float* out = (float*)d_out;
  const int nrec = TT * BB;
  k_gather<<<dim3(nrec / 4), dim3(256), 0, stream>>>(acts, target, ws);
  k_alpha<<<dim3(BB), dim3(128), 0, stream>>>(target, sizes, lablens, ws);
  k_final<<<dim3(1), dim3(64), 0, stream>>>(ws, out);
}